// Round 2
// baseline (688.746 us; speedup 1.0000x reference)
//
#include <hip/hip_runtime.h>
#include <stdint.h>

typedef __attribute__((ext_vector_type(8))) __bf16 bf16x8;
typedef __attribute__((ext_vector_type(4))) float f32x4;

#define S_TOK 1024
#define H_DIM 768
#define NLBL  50
#define NEDGE 65536
#define NSEG  (S_TOK * NLBL)      // 51200
#define NSPAN 9171
#define MPAD  9216                // 72 * 128
#define DDIM  2304
#define KTOP  409
#define KGCN  (NLBL * H_DIM)      // 38400

__device__ __forceinline__ unsigned short f32_to_bf16u(float f) {
  unsigned u = __float_as_uint(f);
  u += 0x7fffu + ((u >> 16) & 1u);          // round-to-nearest-even
  return (unsigned short)(u >> 16);
}
__device__ __forceinline__ float bf16u_to_f32(unsigned short h) {
  return __uint_as_float(((unsigned)h) << 16);
}
__device__ __forceinline__ unsigned pack_bf16(float lo, float hi) {
  return ((unsigned)f32_to_bf16u(hi) << 16) | f32_to_bf16u(lo);
}

// async global->LDS, 16B per lane, wave-uniform LDS base (m97 pattern)
__device__ __forceinline__ void gl_lds16(const void* g, void* l) {
  __builtin_amdgcn_global_load_lds((const __attribute__((address_space(1))) void*)g,
                                   (__attribute__((address_space(3))) void*)l, 16, 0, 0);
}

// ---------------- transpose + fp32->bf16 convert: in (R x C) -> out (C x R) ----
__global__ __launch_bounds__(256) void transpose_conv(
    const float* __restrict__ in, unsigned short* __restrict__ out, int R, int C) {
  __shared__ float tile[32][33];
  int tx = threadIdx.x & 31, ty = threadIdx.x >> 5;   // 32 x 8
  int c0 = blockIdx.x * 32, r0 = blockIdx.y * 32;
#pragma unroll
  for (int i = 0; i < 4; i++)
    tile[ty + 8 * i][tx] = in[(size_t)(r0 + ty + 8 * i) * C + c0 + tx];
  __syncthreads();
#pragma unroll
  for (int i = 0; i < 4; i++)
    out[(size_t)(c0 + ty + 8 * i) * R + r0 + tx] = f32_to_bf16u(tile[tx][ty + 8 * i]);
}

// ---------------- edge bucketing ----------------
__global__ void edge_count(const int* __restrict__ edges, int* __restrict__ seg_count) {
  int e = blockIdx.x * 256 + threadIdx.x;
  if (e >= NEDGE) return;
  int tgt = edges[e * 3 + 1], lbl = edges[e * 3 + 2];
  atomicAdd(&seg_count[tgt * NLBL + lbl], 1);
}

__global__ __launch_bounds__(1024) void scan_kernel(
    const int* __restrict__ cnt, int* __restrict__ offs) {
  __shared__ int part[1024];
  int t = threadIdx.x;
  int base = t * 50;                    // 1024 * 50 = 51200
  int s = 0;
  for (int i = 0; i < 50; i++) s += cnt[base + i];
  part[t] = s;
  __syncthreads();
  for (int o = 1; o < 1024; o <<= 1) {
    int v = part[t];
    int u = (t >= o) ? part[t - o] : 0;
    __syncthreads();
    part[t] = v + u;
    __syncthreads();
  }
  int ex = part[t] - s;                 // exclusive base for this thread's range
  for (int i = 0; i < 50; i++) { offs[base + i] = ex; ex += cnt[base + i]; }
  if (t == 1023) offs[NSEG] = ex;       // total = NEDGE
}

__global__ void edge_scatter(const int* __restrict__ edges, const int* __restrict__ seg_off,
                             int* __restrict__ seg_cursor, int* __restrict__ sorted_src) {
  int e = blockIdx.x * 256 + threadIdx.x;
  if (e >= NEDGE) return;
  int src = edges[e * 3], tgt = edges[e * 3 + 1], lbl = edges[e * 3 + 2];
  int seg = tgt * NLBL + lbl;
  int pos = seg_off[seg] + atomicAdd(&seg_cursor[seg], 1);
  sorted_src[pos] = src;
}

// one wave per segment: agg[seg][h] = sum over edges of x[src][h], write bf16
// lane handles h = {2*(lane+64i), 2*(lane+64i)+1} -> float2 reads, u32 packed writes
__global__ __launch_bounds__(256) void agg_kernel(
    const float* __restrict__ x, const int* __restrict__ seg_off,
    const int* __restrict__ sorted_src, unsigned short* __restrict__ agg) {
  int wave = threadIdx.x >> 6, lane = threadIdx.x & 63;
  int seg = blockIdx.x * 4 + wave;
  int b = seg_off[seg], e = seg_off[seg + 1];
  float2 acc[6];
#pragma unroll
  for (int i = 0; i < 6; i++) acc[i] = make_float2(0.f, 0.f);
  for (int p = b; p < e; p++) {
    const float2* row2 = (const float2*)(x + (size_t)sorted_src[p] * H_DIM);
#pragma unroll
    for (int i = 0; i < 6; i++) {
      float2 v = row2[lane + 64 * i];
      acc[i].x += v.x; acc[i].y += v.y;
    }
  }
  unsigned* dst = (unsigned*)(agg + (size_t)seg * H_DIM);
#pragma unroll
  for (int i = 0; i < 6; i++) dst[lane + 64 * i] = pack_bf16(acc[i].x, acc[i].y);
}

// ---------------- bf16 MFMA GEMM, 128x128 tile, BK=64, global_load_lds staging --
// A: M x K row-major (lda=K), B: N x K row-major (ldb=K)  [B pre-transposed]
// EPI 0: split-K, atomicAdd fp32 into C (M x Nn)
// EPI 1: scores[m] += sum_n relu(acc + b1[n]) * w2[n]   (guard m < M)
template <int EPI>
__global__ __launch_bounds__(256) void gemm_bf16(
    const __bf16* __restrict__ A, const __bf16* __restrict__ B,
    float* __restrict__ C, const float* __restrict__ b1, const float* __restrict__ w2,
    int M, int Nn, int K, int mb, int nb, int kChunk) {
  __shared__ __bf16 As[128 * 64];     // unpadded: required by global_load_lds layout
  __shared__ __bf16 Bs[128 * 64];
  int bid = blockIdx.x;
  int im = bid % mb; bid /= mb;
  int in_ = bid % nb; int ik = bid / nb;
  int m0 = im * 128, n0 = in_ * 128;
  int k0 = ik * kChunk, k1 = k0 + kChunk;

  int t = threadIdx.x;
  int wave = t >> 6, lane = t & 63;
  int wr = wave >> 1, wc = wave & 1;
  int quad = lane >> 4, l15 = lane & 15;
  int lrow = lane >> 3, lk = (lane & 7) << 3;   // within 8-row x 64-k chunk

  f32x4 acc[4][4];
  f32x4 zero = {0.f, 0.f, 0.f, 0.f};
#pragma unroll
  for (int mi = 0; mi < 4; mi++)
#pragma unroll
    for (int ni = 0; ni < 4; ni++) acc[mi][ni] = zero;

  for (int kt = k0; kt < k1; kt += 64) {
    // stage 128x64 A and B tiles: 16 chunks of 8 rows, 4 per wave, 16B/lane
#pragma unroll
    for (int i = 0; i < 4; i++) {
      int c = i * 4 + wave;
      int r = c * 8 + lrow;
      gl_lds16(A + (size_t)(m0 + r) * K + kt + lk, &As[c * 512]);
      gl_lds16(B + (size_t)(n0 + r) * K + kt + lk, &Bs[c * 512]);
    }
    __syncthreads();   // drains vmcnt -> LDS valid
#pragma unroll
    for (int kk = 0; kk < 64; kk += 32) {
      bf16x8 af[4], bg[4];
#pragma unroll
      for (int mi = 0; mi < 4; mi++)
        af[mi] = *(const bf16x8*)&As[(wr * 64 + mi * 16 + l15) * 64 + kk + quad * 8];
#pragma unroll
      for (int ni = 0; ni < 4; ni++)
        bg[ni] = *(const bf16x8*)&Bs[(wc * 64 + ni * 16 + l15) * 64 + kk + quad * 8];
#pragma unroll
      for (int mi = 0; mi < 4; mi++)
#pragma unroll
        for (int ni = 0; ni < 4; ni++)
          acc[mi][ni] = __builtin_amdgcn_mfma_f32_16x16x32_bf16(af[mi], bg[ni], acc[mi][ni], 0, 0, 0);
    }
    __syncthreads();
  }

  if (EPI == 0) {
#pragma unroll
    for (int mi = 0; mi < 4; mi++) {
      int gm = m0 + wr * 64 + mi * 16 + quad * 4;
#pragma unroll
      for (int ni = 0; ni < 4; ni++) {
        int gn = n0 + wc * 64 + ni * 16 + l15;
#pragma unroll
        for (int r = 0; r < 4; r++)
          atomicAdd(&C[(size_t)(gm + r) * Nn + gn], acc[mi][ni][r]);
      }
    }
  } else {
    float b1v[4], w2v[4];
#pragma unroll
    for (int ni = 0; ni < 4; ni++) {
      int gn = n0 + wc * 64 + ni * 16 + l15;
      b1v[ni] = b1[gn];
      w2v[ni] = w2[gn];
    }
#pragma unroll
    for (int mi = 0; mi < 4; mi++) {
      int gm = m0 + wr * 64 + mi * 16 + quad * 4;
      float part[4] = {0.f, 0.f, 0.f, 0.f};
#pragma unroll
      for (int ni = 0; ni < 4; ni++)
#pragma unroll
        for (int r = 0; r < 4; r++)
          part[r] += fmaxf(acc[mi][ni][r] + b1v[ni], 0.f) * w2v[ni];
#pragma unroll
      for (int o = 1; o < 16; o <<= 1)
#pragma unroll
        for (int r = 0; r < 4; r++) part[r] += __shfl_xor(part[r], o, 64);
      if (l15 == 0) {
#pragma unroll
        for (int r = 0; r < 4; r++)
          if (gm + r < M) atomicAdd(&C[gm + r], part[r]);
      }
    }
  }
}

// ---------------- emb = x + relu((C1 + cnt@gcn_b)/degree) ----------------
__global__ __launch_bounds__(256) void emb_kernel(
    const float* __restrict__ x, const float* __restrict__ C1,
    const int* __restrict__ seg_count, const float* __restrict__ gcn_b,
    float* __restrict__ emb) {
  int s = blockIdx.x;
  __shared__ float cntf[NLBL];
  __shared__ float degs;
  int t = threadIdx.x;
  if (t < NLBL) cntf[t] = (float)seg_count[s * NLBL + t];
  __syncthreads();
  if (t == 0) {
    float d = 0.f;
    for (int l = 0; l < NLBL; l++) d += cntf[l];
    degs = fmaxf(d, 1.f);
  }
  __syncthreads();
  float dinv = 1.f / degs;
  for (int h = t; h < H_DIM; h += 256) {
    float bias = 0.f;
    for (int l = 0; l < NLBL; l++) bias += cntf[l] * gcn_b[l * H_DIM + h];
    float v = (C1[(size_t)s * H_DIM + h] + bias) * dinv;
    emb[(size_t)s * H_DIM + h] = x[(size_t)s * H_DIM + h] + fmaxf(v, 0.f);
  }
}

// ---------------- span attention + span_vec (bf16), one wave per span ------
__global__ __launch_bounds__(256) void span_kernel(
    const float* __restrict__ emb, const int* __restrict__ starts,
    const int* __restrict__ ends, const float* __restrict__ attn_w,
    unsigned short* __restrict__ spanv, int nspan) {
  int sp = blockIdx.x * 4 + (threadIdx.x >> 6);
  if (sp >= nspan) return;
  int lane = threadIdx.x & 63;
  int start = starts[sp], end = ends[sp];
  int len = end - start + 1;            // 2..10 (uniform per wave)
  const float2* aw2 = (const float2*)attn_w;
  float sc[10];
  for (int w = 0; w < len; w++) {
    const float2* row2 = (const float2*)(emb + (size_t)(start + w) * H_DIM);
    float p = 0.f;
#pragma unroll
    for (int i = 0; i < 6; i++) {
      float2 v = row2[lane + 64 * i];
      float2 a = aw2[lane + 64 * i];
      p += v.x * a.x + v.y * a.y;
    }
#pragma unroll
    for (int o = 1; o < 64; o <<= 1) p += __shfl_xor(p, o, 64);
    sc[w] = p;
  }
  float m = -1e30f;
  for (int w = 0; w < len; w++) m = fmaxf(m, sc[w]);
  float aw[10];
  float ssum = 0.f;
  for (int w = 0; w < len; w++) { aw[w] = __expf(sc[w] - m); ssum += aw[w]; }
  float inv = 1.f / ssum;
  const float2* rs2 = (const float2*)(emb + (size_t)start * H_DIM);
  const float2* re2 = (const float2*)(emb + (size_t)end * H_DIM);
  unsigned* out32 = (unsigned*)(spanv + (size_t)sp * DDIM);
#pragma unroll
  for (int i = 0; i < 6; i++) {
    int j = lane + 64 * i;
    float ax = 0.f, ay = 0.f;
    for (int w = 0; w < len; w++) {
      float2 v = ((const float2*)(emb + (size_t)(start + w) * H_DIM))[j];
      ax += aw[w] * v.x; ay += aw[w] * v.y;
    }
    float2 vs = rs2[j], ve = re2[j];
    out32[j] = pack_bf16(vs.x, vs.y);
    out32[384 + j] = pack_bf16(ve.x, ve.y);
    out32[768 + j] = pack_bf16(ax * inv, ay * inv);
  }
}

// ---------------- top-k (radix select + small bitonic), single block -------
__device__ __forceinline__ unsigned score_key(float s) {
  unsigned b = __float_as_uint(s);
  return (b & 0x80000000u) ? ~b : (b | 0x80000000u);   // ascending-order key
}

__global__ __launch_bounds__(1024) void topk_kernel(
    const float* __restrict__ scores, int* __restrict__ topk_idx) {
  __shared__ unsigned skeys[NSPAN];          // 36.7 KB: stage once, 5 passes read LDS
  __shared__ int hist[256];
  __shared__ unsigned sh_prefix;
  __shared__ int sh_remaining, sh_cnt;
  __shared__ unsigned long long keys[512];
  int t = threadIdx.x;
  for (int i = t; i < NSPAN; i += 1024) skeys[i] = score_key(scores[i]);
  unsigned prefix = 0;
  int remaining = KTOP;
  for (int p = 3; p >= 0; p--) {
    for (int b = t; b < 256; b += 1024) hist[b] = 0;
    __syncthreads();
    for (int i = t; i < NSPAN; i += 1024) {
      unsigned u = skeys[i];
      bool ok = (p == 3) ? true : ((u >> ((p + 1) * 8)) == prefix);
      if (ok) atomicAdd(&hist[(u >> (p * 8)) & 0xff], 1);
    }
    __syncthreads();
    if (t == 0) {
      int rem = remaining;
      int b = 255;
      for (;; b--) {
        int c = hist[b];
        if (c >= rem) break;
        rem -= c;
      }
      sh_prefix = (prefix << 8) | (unsigned)b;
      sh_remaining = rem;
    }
    __syncthreads();
    prefix = sh_prefix;
    remaining = sh_remaining;
    __syncthreads();
  }
  unsigned kth = prefix;
  if (t == 0) sh_cnt = 0;
  __syncthreads();
  for (int i = t; i < NSPAN; i += 1024) {
    unsigned u = skeys[i];
    if (u >= kth) {
      int pos = atomicAdd(&sh_cnt, 1);
      if (pos < 512) keys[pos] = (((unsigned long long)(~u)) << 32) | (unsigned)i;
    }
  }
  __syncthreads();
  int cnt = sh_cnt < 512 ? sh_cnt : 512;
  for (int i = t; i < 512; i += 1024)
    if (i >= cnt) keys[i] = ~0ull;
  __syncthreads();
  // bitonic sort 512 ascending: key = (~u, idx) -> score desc, idx asc
  for (int ksz = 2; ksz <= 512; ksz <<= 1)
    for (int j = ksz >> 1; j > 0; j >>= 1) {
      if (t < 512) {
        int ixj = t ^ j;
        if (ixj > t) {
          unsigned long long a = keys[t], b = keys[ixj];
          bool up = ((t & ksz) == 0);
          if (up ? (a > b) : (a < b)) { keys[t] = b; keys[ixj] = a; }
        }
      }
      __syncthreads();
    }
  for (int i = t; i < KTOP; i += 1024) topk_idx[i] = (int)(keys[i] & 0xffffffffu);
}

// ---------------- s_i / s_j for pruned spans ----------------
__global__ __launch_bounds__(256) void sij_kernel(
    const unsigned short* __restrict__ spanv, const int* __restrict__ topk_idx,
    const float* __restrict__ antW, float* __restrict__ s_i, float* __restrict__ s_j) {
  int r = blockIdx.x;
  int idx = topk_idx[r];
  const unsigned short* row = spanv + (size_t)idx * DDIM;
  int t = threadIdx.x, lane = t & 63, wave = t >> 6;
  float pi = 0.f, pj = 0.f;
  for (int d = t; d < DDIM; d += 256) {
    float v = bf16u_to_f32(row[d]);
    pi += v * antW[d];
    pj += v * antW[DDIM + d];
  }
  for (int o = 32; o; o >>= 1) {
    pi += __shfl_down(pi, o, 64);
    pj += __shfl_down(pj, o, 64);
  }
  __shared__ float ri[4], rj[4];
  if (lane == 0) { ri[wave] = pi; rj[wave] = pj; }
  __syncthreads();
  if (t == 0) {
    s_i[r] = ri[0] + ri[1] + ri[2] + ri[3];
    s_j[r] = rj[0] + rj[1] + rj[2] + rj[3];
  }
}

// ---------------- final antecedent scores ----------------
__global__ void out_kernel(const float* __restrict__ s_i, const float* __restrict__ s_j,
                           const float* __restrict__ ant_b, float* __restrict__ out) {
  int idx = blockIdx.x * 256 + threadIdx.x;
  if (idx >= KTOP * (KTOP + 1)) return;
  int i = idx / (KTOP + 1), c = idx % (KTOP + 1);
  float v;
  if (c == 0) v = 0.f;
  else {
    int j = c - 1;
    v = (j >= i) ? -10000.f : (s_i[i] + s_j[j] + ant_b[0]);
  }
  out[idx] = v;
}

extern "C" void kernel_launch(void* const* d_in, const int* in_sizes, int n_in,
                              void* d_out, int out_size, void* d_ws, size_t ws_size,
                              hipStream_t stream) {
  const float* x      = (const float*)d_in[0];
  const int*   edges  = (const int*)d_in[1];
  const float* gcn_W  = (const float*)d_in[2];
  const float* gcn_b  = (const float*)d_in[3];
  const float* attn_w = (const float*)d_in[4];
  // d_in[5] attn_b: softmax-shift invariant, unused
  const float* ms_W1  = (const float*)d_in[6];
  const float* ms_b1  = (const float*)d_in[7];
  const float* ms_W2  = (const float*)d_in[8];
  // d_in[9] ms_b2: constant shift, doesn't affect top-k order or output
  const float* ant_W  = (const float*)d_in[10];
  const float* ant_b  = (const float*)d_in[11];
  const int* starts   = (const int*)d_in[12];
  const int* ends     = (const int*)d_in[13];
  // d_in[14] topk = 409 (hardcoded; fixed by problem sizes)

  size_t off = 0;
  char* wsb = (char*)d_ws;
  auto alloc = [&](size_t bytes) -> void* {
    void* p = wsb + off;
    off += (bytes + 255) & ~(size_t)255;
    return p;
  };
  unsigned short* agg   = (unsigned short*)alloc((size_t)S_TOK * KGCN * 2);   // 78.6 MB
  unsigned short* Wt1   = (unsigned short*)alloc((size_t)H_DIM * KGCN * 2);   // 59.0 MB
  unsigned short* Wt2   = (unsigned short*)alloc((size_t)DDIM * DDIM * 2);    // 10.6 MB
  unsigned short* spanv = (unsigned short*)alloc((size_t)MPAD * DDIM * 2);    // 42.5 MB
  int* seg_count  = (int*)alloc(NSEG * 4);
  int* seg_off    = (int*)alloc((NSEG + 4) * 4);
  int* seg_cursor = (int*)alloc(NSEG * 4);
  int* sorted_src = (int*)alloc(NEDGE * 4);
  float* C1     = (float*)alloc((size_t)S_TOK * H_DIM * 4);
  float* emb    = (float*)alloc((size_t)S_TOK * H_DIM * 4);
  float* scores = (float*)alloc(MPAD * 4);
  int* topk_idx = (int*)alloc(512 * 4);
  float* s_i    = (float*)alloc(512 * 4);
  float* s_j    = (float*)alloc(512 * 4);
  (void)ws_size; (void)in_sizes; (void)n_in; (void)out_size;

  hipMemsetAsync(seg_count, 0, NSEG * 4, stream);
  hipMemsetAsync(seg_cursor, 0, NSEG * 4, stream);
  hipMemsetAsync(C1, 0, (size_t)S_TOK * H_DIM * 4, stream);
  hipMemsetAsync(scores, 0, MPAD * 4, stream);

  dim3 b256(256);
  transpose_conv<<<dim3(H_DIM / 32, KGCN / 32), b256, 0, stream>>>(gcn_W, Wt1, KGCN, H_DIM);
  transpose_conv<<<dim3(DDIM / 32, DDIM / 32), b256, 0, stream>>>(ms_W1, Wt2, DDIM, DDIM);
  edge_count<<<NEDGE / 256, b256, 0, stream>>>(edges, seg_count);
  scan_kernel<<<1, 1024, 0, stream>>>(seg_count, seg_off);
  edge_scatter<<<NEDGE / 256, b256, 0, stream>>>(edges, seg_off, seg_cursor, sorted_src);
  agg_kernel<<<NSEG / 4, b256, 0, stream>>>(x, seg_off, sorted_src, agg);
  // GEMM1: (1024 x 38400) @ (38400 x 768), split-K=24 (kChunk=1600)
  gemm_bf16<0><<<8 * 6 * 24, b256, 0, stream>>>((const __bf16*)agg, (const __bf16*)Wt1, C1,
                                                nullptr, nullptr, S_TOK, H_DIM, KGCN, 8, 6, 1600);
  emb_kernel<<<S_TOK, b256, 0, stream>>>(x, C1, seg_count, gcn_b, emb);
  span_kernel<<<(NSPAN + 3) / 4, b256, 0, stream>>>(emb, starts, ends, attn_w, spanv, NSPAN);
  // GEMM2: (9171 x 2304) @ (2304 x 2304) with fused relu(+b1)*W2 row-reduce epilogue
  gemm_bf16<1><<<72 * 18, b256, 0, stream>>>((const __bf16*)spanv, (const __bf16*)Wt2, scores,
                                             ms_b1, ms_W2, NSPAN, DDIM, DDIM, 72, 18, DDIM);
  topk_kernel<<<1, 1024, 0, stream>>>(scores, topk_idx);
  sij_kernel<<<KTOP, b256, 0, stream>>>(spanv, topk_idx, ant_W, s_i, s_j);
  out_kernel<<<(KTOP * (KTOP + 1) + 255) / 256, b256, 0, stream>>>(s_i, s_j, ant_b, (float*)d_out);
}

// Round 3
// 686.541 us; speedup vs baseline: 1.0032x; 1.0032x over previous
//
#include <hip/hip_runtime.h>
#include <stdint.h>

typedef __attribute__((ext_vector_type(8))) __bf16 bf16x8;
typedef __attribute__((ext_vector_type(4))) float f32x4;

#define S_TOK 1024
#define H_DIM 768
#define NLBL  50
#define NEDGE 65536
#define NSEG  (S_TOK * NLBL)      // 51200
#define NSPAN 9171
#define MPAD  9216                // 72 * 128
#define DDIM  2304
#define KTOP  409
#define KGCN  (NLBL * H_DIM)      // 38400
#define SPLITK1 12                // 600 k-iters / 12 = 50 per block

__device__ __forceinline__ unsigned short f32_to_bf16u(float f) {
  unsigned u = __float_as_uint(f);
  u += 0x7fffu + ((u >> 16) & 1u);          // round-to-nearest-even
  return (unsigned short)(u >> 16);
}
__device__ __forceinline__ float bf16u_to_f32(unsigned short h) {
  return __uint_as_float(((unsigned)h) << 16);
}
__device__ __forceinline__ unsigned pack_bf16(float lo, float hi) {
  return ((unsigned)f32_to_bf16u(hi) << 16) | f32_to_bf16u(lo);
}

// async global->LDS, 16B per lane, wave-uniform LDS base (m97 pattern)
__device__ __forceinline__ void gl_lds16(const void* g, void* l) {
  __builtin_amdgcn_global_load_lds((const __attribute__((address_space(1))) void*)g,
                                   (__attribute__((address_space(3))) void*)l, 16, 0, 0);
}

// ---------------- transpose + fp32->bf16 convert: in (R x C) -> out (C x R) ----
__global__ __launch_bounds__(256) void transpose_conv(
    const float* __restrict__ in, unsigned short* __restrict__ out, int R, int C) {
  __shared__ float tile[32][33];
  int tx = threadIdx.x & 31, ty = threadIdx.x >> 5;   // 32 x 8
  int c0 = blockIdx.x * 32, r0 = blockIdx.y * 32;
#pragma unroll
  for (int i = 0; i < 4; i++)
    tile[ty + 8 * i][tx] = in[(size_t)(r0 + ty + 8 * i) * C + c0 + tx];
  __syncthreads();
#pragma unroll
  for (int i = 0; i < 4; i++)
    out[(size_t)(c0 + ty + 8 * i) * R + r0 + tx] = f32_to_bf16u(tile[tx][ty + 8 * i]);
}

// ---------------- edge bucketing ----------------
__global__ void edge_count(const int* __restrict__ edges, int* __restrict__ seg_count) {
  int e = blockIdx.x * 256 + threadIdx.x;
  if (e >= NEDGE) return;
  int tgt = edges[e * 3 + 1], lbl = edges[e * 3 + 2];
  atomicAdd(&seg_count[tgt * NLBL + lbl], 1);
}

__global__ __launch_bounds__(1024) void scan_kernel(
    const int* __restrict__ cnt, int* __restrict__ offs) {
  __shared__ int part[1024];
  int t = threadIdx.x;
  int base = t * 50;                    // 1024 * 50 = 51200
  int s = 0;
  for (int i = 0; i < 50; i++) s += cnt[base + i];
  part[t] = s;
  __syncthreads();
  for (int o = 1; o < 1024; o <<= 1) {
    int v = part[t];
    int u = (t >= o) ? part[t - o] : 0;
    __syncthreads();
    part[t] = v + u;
    __syncthreads();
  }
  int ex = part[t] - s;                 // exclusive base for this thread's range
  for (int i = 0; i < 50; i++) { offs[base + i] = ex; ex += cnt[base + i]; }
  if (t == 1023) offs[NSEG] = ex;       // total = NEDGE
}

__global__ void edge_scatter(const int* __restrict__ edges, const int* __restrict__ seg_off,
                             int* __restrict__ seg_cursor, int* __restrict__ sorted_src) {
  int e = blockIdx.x * 256 + threadIdx.x;
  if (e >= NEDGE) return;
  int src = edges[e * 3], tgt = edges[e * 3 + 1], lbl = edges[e * 3 + 2];
  int seg = tgt * NLBL + lbl;
  int pos = seg_off[seg] + atomicAdd(&seg_cursor[seg], 1);
  sorted_src[pos] = src;
}

// one wave per segment: agg[seg][h] = sum over edges of x[src][h], write bf16
__global__ __launch_bounds__(256) void agg_kernel(
    const float* __restrict__ x, const int* __restrict__ seg_off,
    const int* __restrict__ sorted_src, unsigned short* __restrict__ agg) {
  int wave = threadIdx.x >> 6, lane = threadIdx.x & 63;
  int seg = blockIdx.x * 4 + wave;
  int b = seg_off[seg], e = seg_off[seg + 1];
  float2 acc[6];
#pragma unroll
  for (int i = 0; i < 6; i++) acc[i] = make_float2(0.f, 0.f);
  for (int p = b; p < e; p++) {
    const float2* row2 = (const float2*)(x + (size_t)sorted_src[p] * H_DIM);
#pragma unroll
    for (int i = 0; i < 6; i++) {
      float2 v = row2[lane + 64 * i];
      acc[i].x += v.x; acc[i].y += v.y;
    }
  }
  unsigned* dst = (unsigned*)(agg + (size_t)seg * H_DIM);
#pragma unroll
  for (int i = 0; i < 6; i++) dst[lane + 64 * i] = pack_bf16(acc[i].x, acc[i].y);
}

// ---------------- bf16 MFMA GEMM, 128x128 tile, BK=64, global_load_lds + XOR swizzle --
// LDS layout: row r (stride 64), logical k-chunk ci (8 bf16) stored at position ci^(r&7).
// Staging lane permutation keeps global 16B chunks contiguous; reads spread 8 bank groups.
// A: M x K row-major, B: N x K row-major (pre-transposed)
// EPI 0: split-K partials, plain stores to C + ik*M*Nn
// EPI 1: scores[m] += sum_n relu(acc + b1[n]) * w2[n]   (guard m < M)
template <int EPI>
__global__ __launch_bounds__(256) void gemm_bf16(
    const __bf16* __restrict__ A, const __bf16* __restrict__ B,
    float* __restrict__ C, const float* __restrict__ b1, const float* __restrict__ w2,
    int M, int Nn, int K, int mb, int nb, int kChunk) {
  __shared__ __bf16 As[128 * 64];
  __shared__ __bf16 Bs[128 * 64];
  int bid = blockIdx.x;
  int im = bid % mb; bid /= mb;
  int in_ = bid % nb; int ik = bid / nb;
  int m0 = im * 128, n0 = in_ * 128;
  int k0 = ik * kChunk, k1 = k0 + kChunk;

  int t = threadIdx.x;
  int wave = t >> 6, lane = t & 63;
  int wr = wave >> 1, wc = wave & 1;
  int quad = lane >> 4, l15 = lane & 15;
  int h8 = l15 & 7;                              // row&7 for fragment reads
  int lrow = lane >> 3;                          // 0..7 within 8-row chunk
  int lk = ((lane & 7) ^ lrow) << 3;             // swizzled global k-chunk

  f32x4 acc[4][4];
  f32x4 zero = {0.f, 0.f, 0.f, 0.f};
#pragma unroll
  for (int mi = 0; mi < 4; mi++)
#pragma unroll
    for (int ni = 0; ni < 4; ni++) acc[mi][ni] = zero;

  for (int kt = k0; kt < k1; kt += 64) {
    // stage 128x64 A and B tiles: 16 chunks of 8 rows, 4 per wave, 16B/lane
#pragma unroll
    for (int i = 0; i < 4; i++) {
      int c = i * 4 + wave;
      int r = c * 8 + lrow;
      gl_lds16(A + (size_t)(m0 + r) * K + kt + lk, &As[c * 512]);
      gl_lds16(B + (size_t)(n0 + r) * K + kt + lk, &Bs[c * 512]);
    }
    __syncthreads();   // drains vmcnt -> LDS valid
#pragma unroll
    for (int kk = 0; kk < 64; kk += 32) {
      bf16x8 af[4], bg[4];
      int ci = (kk >> 3) + quad;                 // logical chunk 0..7
      int sw = (ci ^ h8) << 3;                   // swizzled element offset
#pragma unroll
      for (int mi = 0; mi < 4; mi++)
        af[mi] = *(const bf16x8*)&As[(wr * 64 + mi * 16 + l15) * 64 + sw];
#pragma unroll
      for (int ni = 0; ni < 4; ni++)
        bg[ni] = *(const bf16x8*)&Bs[(wc * 64 + ni * 16 + l15) * 64 + sw];
#pragma unroll
      for (int mi = 0; mi < 4; mi++)
#pragma unroll
        for (int ni = 0; ni < 4; ni++)
          acc[mi][ni] = __builtin_amdgcn_mfma_f32_16x16x32_bf16(af[mi], bg[ni], acc[mi][ni], 0, 0, 0);
    }
    __syncthreads();
  }

  if (EPI == 0) {
    float* Cp = C + (size_t)ik * M * Nn;
#pragma unroll
    for (int mi = 0; mi < 4; mi++) {
      int gm = m0 + wr * 64 + mi * 16 + quad * 4;
#pragma unroll
      for (int ni = 0; ni < 4; ni++) {
        int gn = n0 + wc * 64 + ni * 16 + l15;
#pragma unroll
        for (int r = 0; r < 4; r++)
          Cp[(size_t)(gm + r) * Nn + gn] = acc[mi][ni][r];
      }
    }
  } else {
    float b1v[4], w2v[4];
#pragma unroll
    for (int ni = 0; ni < 4; ni++) {
      int gn = n0 + wc * 64 + ni * 16 + l15;
      b1v[ni] = b1[gn];
      w2v[ni] = w2[gn];
    }
#pragma unroll
    for (int mi = 0; mi < 4; mi++) {
      int gm = m0 + wr * 64 + mi * 16 + quad * 4;
      float part[4] = {0.f, 0.f, 0.f, 0.f};
#pragma unroll
      for (int ni = 0; ni < 4; ni++)
#pragma unroll
        for (int r = 0; r < 4; r++)
          part[r] += fmaxf(acc[mi][ni][r] + b1v[ni], 0.f) * w2v[ni];
#pragma unroll
      for (int o = 1; o < 16; o <<= 1)
#pragma unroll
        for (int r = 0; r < 4; r++) part[r] += __shfl_xor(part[r], o, 64);
      if (l15 == 0) {
#pragma unroll
        for (int r = 0; r < 4; r++)
          if (gm + r < M) atomicAdd(&C[gm + r], part[r]);
      }
    }
  }
}

// ------- emb = x + relu((sum_k partials + cnt@gcn_b)/degree) ----------------
__global__ __launch_bounds__(256) void emb_kernel(
    const float* __restrict__ x, const float* __restrict__ partials,
    const int* __restrict__ seg_count, const float* __restrict__ gcn_b,
    float* __restrict__ emb) {
  int s = blockIdx.x;
  __shared__ float cntf[NLBL];
  __shared__ float degs;
  int t = threadIdx.x;
  if (t < NLBL) cntf[t] = (float)seg_count[s * NLBL + t];
  __syncthreads();
  if (t == 0) {
    float d = 0.f;
    for (int l = 0; l < NLBL; l++) d += cntf[l];
    degs = fmaxf(d, 1.f);
  }
  __syncthreads();
  float dinv = 1.f / degs;
  for (int h = t; h < H_DIM; h += 256) {
    float bias = 0.f;
    for (int l = 0; l < NLBL; l++) bias += cntf[l] * gcn_b[l * H_DIM + h];
    float v = bias;
#pragma unroll
    for (int p = 0; p < SPLITK1; p++)
      v += partials[(size_t)p * S_TOK * H_DIM + (size_t)s * H_DIM + h];
    v *= dinv;
    emb[(size_t)s * H_DIM + h] = x[(size_t)s * H_DIM + h] + fmaxf(v, 0.f);
  }
}

// ---------------- span attention + span_vec (bf16), one wave per span ------
__global__ __launch_bounds__(256) void span_kernel(
    const float* __restrict__ emb, const int* __restrict__ starts,
    const int* __restrict__ ends, const float* __restrict__ attn_w,
    unsigned short* __restrict__ spanv, int nspan) {
  int sp = blockIdx.x * 4 + (threadIdx.x >> 6);
  if (sp >= nspan) return;
  int lane = threadIdx.x & 63;
  int start = starts[sp], end = ends[sp];
  int len = end - start + 1;            // 2..10 (uniform per wave)
  const float2* aw2 = (const float2*)attn_w;
  float sc[10];
  for (int w = 0; w < len; w++) {
    const float2* row2 = (const float2*)(emb + (size_t)(start + w) * H_DIM);
    float p = 0.f;
#pragma unroll
    for (int i = 0; i < 6; i++) {
      float2 v = row2[lane + 64 * i];
      float2 a = aw2[lane + 64 * i];
      p += v.x * a.x + v.y * a.y;
    }
#pragma unroll
    for (int o = 1; o < 64; o <<= 1) p += __shfl_xor(p, o, 64);
    sc[w] = p;
  }
  float m = -1e30f;
  for (int w = 0; w < len; w++) m = fmaxf(m, sc[w]);
  float aw[10];
  float ssum = 0.f;
  for (int w = 0; w < len; w++) { aw[w] = __expf(sc[w] - m); ssum += aw[w]; }
  float inv = 1.f / ssum;
  const float2* rs2 = (const float2*)(emb + (size_t)start * H_DIM);
  const float2* re2 = (const float2*)(emb + (size_t)end * H_DIM);
  unsigned* out32 = (unsigned*)(spanv + (size_t)sp * DDIM);
#pragma unroll
  for (int i = 0; i < 6; i++) {
    int j = lane + 64 * i;
    float ax = 0.f, ay = 0.f;
    for (int w = 0; w < len; w++) {
      float2 v = ((const float2*)(emb + (size_t)(start + w) * H_DIM))[j];
      ax += aw[w] * v.x; ay += aw[w] * v.y;
    }
    float2 vs = rs2[j], ve = re2[j];
    out32[j] = pack_bf16(vs.x, vs.y);
    out32[384 + j] = pack_bf16(ve.x, ve.y);
    out32[768 + j] = pack_bf16(ax * inv, ay * inv);
  }
}

// ---------------- top-k (radix select + small bitonic), single block -------
__device__ __forceinline__ unsigned score_key(float s) {
  unsigned b = __float_as_uint(s);
  return (b & 0x80000000u) ? ~b : (b | 0x80000000u);   // ascending-order key
}

__global__ __launch_bounds__(1024) void topk_kernel(
    const float* __restrict__ scores, int* __restrict__ topk_idx) {
  __shared__ unsigned skeys[NSPAN];          // 36.7 KB: stage once, passes read LDS
  __shared__ int hist[256];
  __shared__ unsigned sh_prefix;
  __shared__ int sh_remaining, sh_cnt;
  __shared__ unsigned long long keys[512];
  int t = threadIdx.x;
  for (int i = t; i < NSPAN; i += 1024) skeys[i] = score_key(scores[i]);
  unsigned prefix = 0;
  int remaining = KTOP;
  for (int p = 3; p >= 0; p--) {
    for (int b = t; b < 256; b += 1024) hist[b] = 0;
    __syncthreads();
    for (int i = t; i < NSPAN; i += 1024) {
      unsigned u = skeys[i];
      bool ok = (p == 3) ? true : ((u >> ((p + 1) * 8)) == prefix);
      if (ok) atomicAdd(&hist[(u >> (p * 8)) & 0xff], 1);
    }
    __syncthreads();
    if (t == 0) {
      int rem = remaining;
      int b = 255;
      for (;; b--) {
        int c = hist[b];
        if (c >= rem) break;
        rem -= c;
      }
      sh_prefix = (prefix << 8) | (unsigned)b;
      sh_remaining = rem;
    }
    __syncthreads();
    prefix = sh_prefix;
    remaining = sh_remaining;
    __syncthreads();
  }
  unsigned kth = prefix;
  if (t == 0) sh_cnt = 0;
  __syncthreads();
  for (int i = t; i < NSPAN; i += 1024) {
    unsigned u = skeys[i];
    if (u >= kth) {
      int pos = atomicAdd(&sh_cnt, 1);
      if (pos < 512) keys[pos] = (((unsigned long long)(~u)) << 32) | (unsigned)i;
    }
  }
  __syncthreads();
  int cnt = sh_cnt < 512 ? sh_cnt : 512;
  for (int i = t; i < 512; i += 1024)
    if (i >= cnt) keys[i] = ~0ull;
  __syncthreads();
  // bitonic sort 512 ascending: key = (~u, idx) -> score desc, idx asc
  for (int ksz = 2; ksz <= 512; ksz <<= 1)
    for (int j = ksz >> 1; j > 0; j >>= 1) {
      if (t < 512) {
        int ixj = t ^ j;
        if (ixj > t) {
          unsigned long long a = keys[t], b = keys[ixj];
          bool up = ((t & ksz) == 0);
          if (up ? (a > b) : (a < b)) { keys[t] = b; keys[ixj] = a; }
        }
      }
      __syncthreads();
    }
  for (int i = t; i < KTOP; i += 1024) topk_idx[i] = (int)(keys[i] & 0xffffffffu);
}

// ---------------- s_i / s_j for pruned spans ----------------
__global__ __launch_bounds__(256) void sij_kernel(
    const unsigned short* __restrict__ spanv, const int* __restrict__ topk_idx,
    const float* __restrict__ antW, float* __restrict__ s_i, float* __restrict__ s_j) {
  int r = blockIdx.x;
  int idx = topk_idx[r];
  const unsigned short* row = spanv + (size_t)idx * DDIM;
  int t = threadIdx.x, lane = t & 63, wave = t >> 6;
  float pi = 0.f, pj = 0.f;
  for (int d = t; d < DDIM; d += 256) {
    float v = bf16u_to_f32(row[d]);
    pi += v * antW[d];
    pj += v * antW[DDIM + d];
  }
  for (int o = 32; o; o >>= 1) {
    pi += __shfl_down(pi, o, 64);
    pj += __shfl_down(pj, o, 64);
  }
  __shared__ float ri[4], rj[4];
  if (lane == 0) { ri[wave] = pi; rj[wave] = pj; }
  __syncthreads();
  if (t == 0) {
    s_i[r] = ri[0] + ri[1] + ri[2] + ri[3];
    s_j[r] = rj[0] + rj[1] + rj[2] + rj[3];
  }
}

// ---------------- final antecedent scores ----------------
__global__ void out_kernel(const float* __restrict__ s_i, const float* __restrict__ s_j,
                           const float* __restrict__ ant_b, float* __restrict__ out) {
  int idx = blockIdx.x * 256 + threadIdx.x;
  if (idx >= KTOP * (KTOP + 1)) return;
  int i = idx / (KTOP + 1), c = idx % (KTOP + 1);
  float v;
  if (c == 0) v = 0.f;
  else {
    int j = c - 1;
    v = (j >= i) ? -10000.f : (s_i[i] + s_j[j] + ant_b[0]);
  }
  out[idx] = v;
}

extern "C" void kernel_launch(void* const* d_in, const int* in_sizes, int n_in,
                              void* d_out, int out_size, void* d_ws, size_t ws_size,
                              hipStream_t stream) {
  const float* x      = (const float*)d_in[0];
  const int*   edges  = (const int*)d_in[1];
  const float* gcn_W  = (const float*)d_in[2];
  const float* gcn_b  = (const float*)d_in[3];
  const float* attn_w = (const float*)d_in[4];
  // d_in[5] attn_b: softmax-shift invariant, unused
  const float* ms_W1  = (const float*)d_in[6];
  const float* ms_b1  = (const float*)d_in[7];
  const float* ms_W2  = (const float*)d_in[8];
  // d_in[9] ms_b2: constant shift, doesn't affect top-k order or output
  const float* ant_W  = (const float*)d_in[10];
  const float* ant_b  = (const float*)d_in[11];
  const int* starts   = (const int*)d_in[12];
  const int* ends     = (const int*)d_in[13];
  // d_in[14] topk = 409 (hardcoded; fixed by problem sizes)

  size_t off = 0;
  char* wsb = (char*)d_ws;
  auto alloc = [&](size_t bytes) -> void* {
    void* p = wsb + off;
    off += (bytes + 255) & ~(size_t)255;
    return p;
  };
  unsigned short* agg   = (unsigned short*)alloc((size_t)S_TOK * KGCN * 2);   // 78.6 MB
  unsigned short* Wt1   = (unsigned short*)alloc((size_t)H_DIM * KGCN * 2);   // 59.0 MB
  unsigned short* Wt2   = (unsigned short*)alloc((size_t)DDIM * DDIM * 2);    // 10.6 MB
  unsigned short* spanv = (unsigned short*)alloc((size_t)MPAD * DDIM * 2);    // 42.5 MB
  // split-K partials (37.7 MB) alias spanv: consumed by emb_kernel BEFORE span_kernel writes
  float* partials = (float*)spanv;
  int* seg_count  = (int*)alloc(NSEG * 4);
  int* seg_off    = (int*)alloc((NSEG + 4) * 4);
  int* seg_cursor = (int*)alloc(NSEG * 4);
  int* sorted_src = (int*)alloc(NEDGE * 4);
  float* emb    = (float*)alloc((size_t)S_TOK * H_DIM * 4);
  float* scores = (float*)alloc(MPAD * 4);
  int* topk_idx = (int*)alloc(512 * 4);
  float* s_i    = (float*)alloc(512 * 4);
  float* s_j    = (float*)alloc(512 * 4);
  (void)ws_size; (void)in_sizes; (void)n_in; (void)out_size;

  hipMemsetAsync(seg_count, 0, NSEG * 4, stream);
  hipMemsetAsync(seg_cursor, 0, NSEG * 4, stream);
  hipMemsetAsync(scores, 0, MPAD * 4, stream);

  dim3 b256(256);
  transpose_conv<<<dim3(H_DIM / 32, KGCN / 32), b256, 0, stream>>>(gcn_W, Wt1, KGCN, H_DIM);
  transpose_conv<<<dim3(DDIM / 32, DDIM / 32), b256, 0, stream>>>(ms_W1, Wt2, DDIM, DDIM);
  edge_count<<<NEDGE / 256, b256, 0, stream>>>(edges, seg_count);
  scan_kernel<<<1, 1024, 0, stream>>>(seg_count, seg_off);
  edge_scatter<<<NEDGE / 256, b256, 0, stream>>>(edges, seg_off, seg_cursor, sorted_src);
  agg_kernel<<<NSEG / 4, b256, 0, stream>>>(x, seg_off, sorted_src, agg);
  // GEMM1: (1024 x 38400) @ (38400 x 768), split-K=12 (kChunk=3200), plain-store partials
  gemm_bf16<0><<<8 * 6 * SPLITK1, b256, 0, stream>>>((const __bf16*)agg, (const __bf16*)Wt1,
                                                     partials, nullptr, nullptr,
                                                     S_TOK, H_DIM, KGCN, 8, 6, 3200);
  emb_kernel<<<S_TOK, b256, 0, stream>>>(x, partials, seg_count, gcn_b, emb);
  span_kernel<<<(NSPAN + 3) / 4, b256, 0, stream>>>(emb, starts, ends, attn_w, spanv, NSPAN);
  // GEMM2: (9171 x 2304) @ (2304 x 2304) with fused relu(+b1)*W2 row-reduce epilogue
  gemm_bf16<1><<<72 * 18, b256, 0, stream>>>((const __bf16*)spanv, (const __bf16*)Wt2, scores,
                                             ms_b1, ms_W2, NSPAN, DDIM, DDIM, 72, 18, DDIM);
  topk_kernel<<<1, 1024, 0, stream>>>(scores, topk_idx);
  sij_kernel<<<KTOP, b256, 0, stream>>>(spanv, topk_idx, ant_W, s_i, s_j);
  out_kernel<<<(KTOP * (KTOP + 1) + 255) / 256, b256, 0, stream>>>(s_i, s_j, ant_b, (float*)d_out);
}

// Round 4
// 589.387 us; speedup vs baseline: 1.1686x; 1.1648x over previous
//
#include <hip/hip_runtime.h>
#include <stdint.h>

typedef __attribute__((ext_vector_type(8))) __bf16 bf16x8;
typedef __attribute__((ext_vector_type(4))) float f32x4;

#define S_TOK 1024
#define H_DIM 768
#define NLBL  50
#define NEDGE 65536
#define NSEG  (S_TOK * NLBL)      // 51200
#define NSPAN 9171
#define MPAD  9216                // 72 * 128
#define DDIM  2304
#define KTOP  409

__device__ __forceinline__ unsigned short f32_to_bf16u(float f) {
  unsigned u = __float_as_uint(f);
  u += 0x7fffu + ((u >> 16) & 1u);          // round-to-nearest-even
  return (unsigned short)(u >> 16);
}
__device__ __forceinline__ float bf16u_to_f32(unsigned short h) {
  return __uint_as_float(((unsigned)h) << 16);
}
__device__ __forceinline__ unsigned pack_bf16(float lo, float hi) {
  return ((unsigned)f32_to_bf16u(hi) << 16) | f32_to_bf16u(lo);
}

// async global->LDS, 16B per lane, wave-uniform LDS base (m97 pattern)
__device__ __forceinline__ void gl_lds16(const void* g, void* l) {
  __builtin_amdgcn_global_load_lds((const __attribute__((address_space(1))) void*)g,
                                   (__attribute__((address_space(3))) void*)l, 16, 0, 0);
}

// ---------------- fp32 -> bf16 convert (X) ----------------
__global__ __launch_bounds__(256) void convert_bf16(
    const float* __restrict__ in, unsigned* __restrict__ out, int npairs) {
  int i = blockIdx.x * 256 + threadIdx.x;
  if (i >= npairs) return;
  float2 v = ((const float2*)in)[i];
  out[i] = pack_bf16(v.x, v.y);
}

// ---------------- transpose + fp32->bf16: per-batch (R x C) -> (C x R) -------
__global__ __launch_bounds__(256) void transpose_conv_b(
    const float* __restrict__ in, unsigned short* __restrict__ out, int R, int C) {
  __shared__ float tile[32][33];
  size_t boff = (size_t)blockIdx.z * R * C;
  int tx = threadIdx.x & 31, ty = threadIdx.x >> 5;   // 32 x 8
  int c0 = blockIdx.x * 32, r0 = blockIdx.y * 32;
#pragma unroll
  for (int i = 0; i < 4; i++)
    tile[ty + 8 * i][tx] = in[boff + (size_t)(r0 + ty + 8 * i) * C + c0 + tx];
  __syncthreads();
#pragma unroll
  for (int i = 0; i < 4; i++)
    out[boff + (size_t)(c0 + ty + 8 * i) * R + r0 + tx] = f32_to_bf16u(tile[tx][ty + 8 * i]);
}

// ---------------- edge counting: per-(tgt,lbl) and per-tgt ----------------
__global__ void edge_count2(const int* __restrict__ edges, int* __restrict__ seg_count,
                            int* __restrict__ tgt_count) {
  int e = blockIdx.x * 256 + threadIdx.x;
  if (e >= NEDGE) return;
  int tgt = edges[e * 3 + 1], lbl = edges[e * 3 + 2];
  atomicAdd(&seg_count[tgt * NLBL + lbl], 1);
  atomicAdd(&tgt_count[tgt], 1);
}

__global__ __launch_bounds__(1024) void scan_t(
    const int* __restrict__ cnt, int* __restrict__ offs) {
  __shared__ int part[1024];
  int t = threadIdx.x;
  int c = cnt[t];
  part[t] = c;
  __syncthreads();
  for (int o = 1; o < 1024; o <<= 1) {
    int v = part[t];
    int u = (t >= o) ? part[t - o] : 0;
    __syncthreads();
    part[t] = v + u;
    __syncthreads();
  }
  offs[t] = part[t] - c;
  if (t == 1023) offs[1024] = part[t];
}

__global__ void edge_scatter_t(const int* __restrict__ edges, const int* __restrict__ tgt_off,
                               int* __restrict__ cursor, int* __restrict__ sorted_row) {
  int e = blockIdx.x * 256 + threadIdx.x;
  if (e >= NEDGE) return;
  int src = edges[e * 3], tgt = edges[e * 3 + 1], lbl = edges[e * 3 + 2];
  int pos = tgt_off[tgt] + atomicAdd(&cursor[tgt], 1);
  sorted_row[pos] = lbl * S_TOK + src;         // direct row index into Y[l][s][:]
}

// ---------------- batched GEMM: Y_l = X @ W_l (bf16 out) ----------------
// A: Xb 1024x768 bf16 (row-major, K=768), B: WtB[l] 768x768 (N-major, K-contig)
// grid (48, 50): blockIdx.x = im + 8*in_, blockIdx.y = l. XOR-swizzled LDS.
__global__ __launch_bounds__(256) void gemm_bt_batched(
    const __bf16* __restrict__ A, const __bf16* __restrict__ B,
    unsigned short* __restrict__ Y) {
  __shared__ __bf16 As[128 * 64];
  __shared__ __bf16 Bs[128 * 64];
  const int K = H_DIM;
  int l = blockIdx.y;
  int im = blockIdx.x & 7, in_ = blockIdx.x >> 3;
  int m0 = im * 128, n0 = in_ * 128;
  const __bf16* Bl = B + (size_t)l * H_DIM * H_DIM;

  int t = threadIdx.x;
  int wave = t >> 6, lane = t & 63;
  int wr = wave >> 1, wc = wave & 1;
  int quad = lane >> 4, l15 = lane & 15;
  int h8 = l15 & 7;
  int lrow = lane >> 3;
  int lk = ((lane & 7) ^ lrow) << 3;

  f32x4 acc[4][4];
  f32x4 zero = {0.f, 0.f, 0.f, 0.f};
#pragma unroll
  for (int mi = 0; mi < 4; mi++)
#pragma unroll
    for (int ni = 0; ni < 4; ni++) acc[mi][ni] = zero;

  for (int kt = 0; kt < K; kt += 64) {
#pragma unroll
    for (int i = 0; i < 4; i++) {
      int c = i * 4 + wave;
      int r = c * 8 + lrow;
      gl_lds16(A + (size_t)(m0 + r) * K + kt + lk, &As[c * 512]);
      gl_lds16(Bl + (size_t)(n0 + r) * K + kt + lk, &Bs[c * 512]);
    }
    __syncthreads();
#pragma unroll
    for (int kk = 0; kk < 64; kk += 32) {
      bf16x8 af[4], bg[4];
      int ci = (kk >> 3) + quad;
      int sw = (ci ^ h8) << 3;
#pragma unroll
      for (int mi = 0; mi < 4; mi++)
        af[mi] = *(const bf16x8*)&As[(wr * 64 + mi * 16 + l15) * 64 + sw];
#pragma unroll
      for (int ni = 0; ni < 4; ni++)
        bg[ni] = *(const bf16x8*)&Bs[(wc * 64 + ni * 16 + l15) * 64 + sw];
#pragma unroll
      for (int mi = 0; mi < 4; mi++)
#pragma unroll
        for (int ni = 0; ni < 4; ni++)
          acc[mi][ni] = __builtin_amdgcn_mfma_f32_16x16x32_bf16(af[mi], bg[ni], acc[mi][ni], 0, 0, 0);
    }
    __syncthreads();
  }

  unsigned short* Yl = Y + (size_t)l * S_TOK * H_DIM;
#pragma unroll
  for (int mi = 0; mi < 4; mi++) {
    int gm = m0 + wr * 64 + mi * 16 + quad * 4;
#pragma unroll
    for (int ni = 0; ni < 4; ni++) {
      int gn = n0 + wc * 64 + ni * 16 + l15;
#pragma unroll
      for (int r = 0; r < 4; r++)
        Yl[(size_t)(gm + r) * H_DIM + gn] = f32_to_bf16u(acc[mi][ni][r]);
    }
  }
}

// ------- gather-sum + bias + degree + relu + residual: emb in one pass -------
// one block per target token; thread t owns dims {t, t+256, t+512}
__global__ __launch_bounds__(256) void gather_emb_kernel(
    const float* __restrict__ x, const unsigned short* __restrict__ Y,
    const int* __restrict__ tgt_off, const int* __restrict__ sorted_row,
    const int* __restrict__ seg_count, const float* __restrict__ gcn_b,
    float* __restrict__ emb) {
  int s = blockIdx.x;
  int t = threadIdx.x;
  int b = tgt_off[s], e = tgt_off[s + 1];
  float a0 = 0.f, a1 = 0.f, a2 = 0.f;
  int p = b;
  for (; p + 1 < e; p += 2) {
    const unsigned short* r0 = Y + (size_t)sorted_row[p] * H_DIM;
    const unsigned short* r1 = Y + (size_t)sorted_row[p + 1] * H_DIM;
    a0 += bf16u_to_f32(r0[t]) + bf16u_to_f32(r1[t]);
    a1 += bf16u_to_f32(r0[t + 256]) + bf16u_to_f32(r1[t + 256]);
    a2 += bf16u_to_f32(r0[t + 512]) + bf16u_to_f32(r1[t + 512]);
  }
  if (p < e) {
    const unsigned short* r0 = Y + (size_t)sorted_row[p] * H_DIM;
    a0 += bf16u_to_f32(r0[t]);
    a1 += bf16u_to_f32(r0[t + 256]);
    a2 += bf16u_to_f32(r0[t + 512]);
  }
  float deg = 0.f, b0 = 0.f, b1 = 0.f, b2 = 0.f;
#pragma unroll 5
  for (int l = 0; l < NLBL; l++) {
    float c = (float)seg_count[s * NLBL + l];
    deg += c;
    b0 += c * gcn_b[l * H_DIM + t];
    b1 += c * gcn_b[l * H_DIM + t + 256];
    b2 += c * gcn_b[l * H_DIM + t + 512];
  }
  float dinv = 1.f / fmaxf(deg, 1.f);
  emb[(size_t)s * H_DIM + t]       = x[(size_t)s * H_DIM + t]       + fmaxf((a0 + b0) * dinv, 0.f);
  emb[(size_t)s * H_DIM + t + 256] = x[(size_t)s * H_DIM + t + 256] + fmaxf((a1 + b1) * dinv, 0.f);
  emb[(size_t)s * H_DIM + t + 512] = x[(size_t)s * H_DIM + t + 512] + fmaxf((a2 + b2) * dinv, 0.f);
}

// ---------------- GEMM2: 128x128 tile, fused relu(+b1)*w2 row-reduce ----------
// A: M x K row-major, B: N x K row-major (pre-transposed). XOR-swizzled LDS.
__global__ __launch_bounds__(256) void gemm_score(
    const __bf16* __restrict__ A, const __bf16* __restrict__ B,
    float* __restrict__ C, const float* __restrict__ b1, const float* __restrict__ w2,
    int M, int Nn, int K, int mb) {
  __shared__ __bf16 As[128 * 64];
  __shared__ __bf16 Bs[128 * 64];
  int bid = blockIdx.x;
  int im = bid % mb, in_ = bid / mb;
  int m0 = im * 128, n0 = in_ * 128;

  int t = threadIdx.x;
  int wave = t >> 6, lane = t & 63;
  int wr = wave >> 1, wc = wave & 1;
  int quad = lane >> 4, l15 = lane & 15;
  int h8 = l15 & 7;
  int lrow = lane >> 3;
  int lk = ((lane & 7) ^ lrow) << 3;

  f32x4 acc[4][4];
  f32x4 zero = {0.f, 0.f, 0.f, 0.f};
#pragma unroll
  for (int mi = 0; mi < 4; mi++)
#pragma unroll
    for (int ni = 0; ni < 4; ni++) acc[mi][ni] = zero;

  for (int kt = 0; kt < K; kt += 64) {
#pragma unroll
    for (int i = 0; i < 4; i++) {
      int c = i * 4 + wave;
      int r = c * 8 + lrow;
      gl_lds16(A + (size_t)(m0 + r) * K + kt + lk, &As[c * 512]);
      gl_lds16(B + (size_t)(n0 + r) * K + kt + lk, &Bs[c * 512]);
    }
    __syncthreads();
#pragma unroll
    for (int kk = 0; kk < 64; kk += 32) {
      bf16x8 af[4], bg[4];
      int ci = (kk >> 3) + quad;
      int sw = (ci ^ h8) << 3;
#pragma unroll
      for (int mi = 0; mi < 4; mi++)
        af[mi] = *(const bf16x8*)&As[(wr * 64 + mi * 16 + l15) * 64 + sw];
#pragma unroll
      for (int ni = 0; ni < 4; ni++)
        bg[ni] = *(const bf16x8*)&Bs[(wc * 64 + ni * 16 + l15) * 64 + sw];
#pragma unroll
      for (int mi = 0; mi < 4; mi++)
#pragma unroll
        for (int ni = 0; ni < 4; ni++)
          acc[mi][ni] = __builtin_amdgcn_mfma_f32_16x16x32_bf16(af[mi], bg[ni], acc[mi][ni], 0, 0, 0);
    }
    __syncthreads();
  }

  float b1v[4], w2v[4];
#pragma unroll
  for (int ni = 0; ni < 4; ni++) {
    int gn = n0 + wc * 64 + ni * 16 + l15;
    b1v[ni] = b1[gn];
    w2v[ni] = w2[gn];
  }
#pragma unroll
  for (int mi = 0; mi < 4; mi++) {
    int gm = m0 + wr * 64 + mi * 16 + quad * 4;
    float part[4] = {0.f, 0.f, 0.f, 0.f};
#pragma unroll
    for (int ni = 0; ni < 4; ni++)
#pragma unroll
      for (int r = 0; r < 4; r++)
        part[r] += fmaxf(acc[mi][ni][r] + b1v[ni], 0.f) * w2v[ni];
#pragma unroll
    for (int o = 1; o < 16; o <<= 1)
#pragma unroll
      for (int r = 0; r < 4; r++) part[r] += __shfl_xor(part[r], o, 64);
    if (l15 == 0) {
#pragma unroll
      for (int r = 0; r < 4; r++)
        if (gm + r < M) atomicAdd(&C[gm + r], part[r]);
    }
  }
}

// ---------------- span attention + span_vec (bf16), one wave per span ------
__global__ __launch_bounds__(256) void span_kernel(
    const float* __restrict__ emb, const int* __restrict__ starts,
    const int* __restrict__ ends, const float* __restrict__ attn_w,
    unsigned short* __restrict__ spanv, int nspan) {
  int sp = blockIdx.x * 4 + (threadIdx.x >> 6);
  if (sp >= nspan) return;
  int lane = threadIdx.x & 63;
  int start = starts[sp], end = ends[sp];
  int len = end - start + 1;            // 2..10 (uniform per wave)
  const float2* aw2 = (const float2*)attn_w;
  float sc[10];
  for (int w = 0; w < len; w++) {
    const float2* row2 = (const float2*)(emb + (size_t)(start + w) * H_DIM);
    float p = 0.f;
#pragma unroll
    for (int i = 0; i < 6; i++) {
      float2 v = row2[lane + 64 * i];
      float2 a = aw2[lane + 64 * i];
      p += v.x * a.x + v.y * a.y;
    }
#pragma unroll
    for (int o = 1; o < 64; o <<= 1) p += __shfl_xor(p, o, 64);
    sc[w] = p;
  }
  float m = -1e30f;
  for (int w = 0; w < len; w++) m = fmaxf(m, sc[w]);
  float aw[10];
  float ssum = 0.f;
  for (int w = 0; w < len; w++) { aw[w] = __expf(sc[w] - m); ssum += aw[w]; }
  float inv = 1.f / ssum;
  const float2* rs2 = (const float2*)(emb + (size_t)start * H_DIM);
  const float2* re2 = (const float2*)(emb + (size_t)end * H_DIM);
  unsigned* out32 = (unsigned*)(spanv + (size_t)sp * DDIM);
#pragma unroll
  for (int i = 0; i < 6; i++) {
    int j = lane + 64 * i;
    float ax = 0.f, ay = 0.f;
    for (int w = 0; w < len; w++) {
      float2 v = ((const float2*)(emb + (size_t)(start + w) * H_DIM))[j];
      ax += aw[w] * v.x; ay += aw[w] * v.y;
    }
    float2 vs = rs2[j], ve = re2[j];
    out32[j] = pack_bf16(vs.x, vs.y);
    out32[384 + j] = pack_bf16(ve.x, ve.y);
    out32[768 + j] = pack_bf16(ax * inv, ay * inv);
  }
}

// ---------------- top-k (radix select + small bitonic), single block -------
__device__ __forceinline__ unsigned score_key(float s) {
  unsigned b = __float_as_uint(s);
  return (b & 0x80000000u) ? ~b : (b | 0x80000000u);   // ascending-order key
}

__global__ __launch_bounds__(1024) void topk_kernel(
    const float* __restrict__ scores, int* __restrict__ topk_idx) {
  __shared__ unsigned skeys[NSPAN];          // 36.7 KB: stage once, passes read LDS
  __shared__ int hist[256];
  __shared__ unsigned sh_prefix;
  __shared__ int sh_remaining, sh_cnt;
  __shared__ unsigned long long keys[512];
  int t = threadIdx.x;
  for (int i = t; i < NSPAN; i += 1024) skeys[i] = score_key(scores[i]);
  unsigned prefix = 0;
  int remaining = KTOP;
  for (int p = 3; p >= 0; p--) {
    for (int b = t; b < 256; b += 1024) hist[b] = 0;
    __syncthreads();
    for (int i = t; i < NSPAN; i += 1024) {
      unsigned u = skeys[i];
      bool ok = (p == 3) ? true : ((u >> ((p + 1) * 8)) == prefix);
      if (ok) atomicAdd(&hist[(u >> (p * 8)) & 0xff], 1);
    }
    __syncthreads();
    if (t == 0) {
      int rem = remaining;
      int b = 255;
      for (;; b--) {
        int c = hist[b];
        if (c >= rem) break;
        rem -= c;
      }
      sh_prefix = (prefix << 8) | (unsigned)b;
      sh_remaining = rem;
    }
    __syncthreads();
    prefix = sh_prefix;
    remaining = sh_remaining;
    __syncthreads();
  }
  unsigned kth = prefix;
  if (t == 0) sh_cnt = 0;
  __syncthreads();
  for (int i = t; i < NSPAN; i += 1024) {
    unsigned u = skeys[i];
    if (u >= kth) {
      int pos = atomicAdd(&sh_cnt, 1);
      if (pos < 512) keys[pos] = (((unsigned long long)(~u)) << 32) | (unsigned)i;
    }
  }
  __syncthreads();
  int cnt = sh_cnt < 512 ? sh_cnt : 512;
  for (int i = t; i < 512; i += 1024)
    if (i >= cnt) keys[i] = ~0ull;
  __syncthreads();
  // bitonic sort 512 ascending: key = (~u, idx) -> score desc, idx asc
  for (int ksz = 2; ksz <= 512; ksz <<= 1)
    for (int j = ksz >> 1; j > 0; j >>= 1) {
      if (t < 512) {
        int ixj = t ^ j;
        if (ixj > t) {
          unsigned long long a = keys[t], b = keys[ixj];
          bool up = ((t & ksz) == 0);
          if (up ? (a > b) : (a < b)) { keys[t] = b; keys[ixj] = a; }
        }
      }
      __syncthreads();
    }
  for (int i = t; i < KTOP; i += 1024) topk_idx[i] = (int)(keys[i] & 0xffffffffu);
}

// ---------------- s_i / s_j for pruned spans ----------------
__global__ __launch_bounds__(256) void sij_kernel(
    const unsigned short* __restrict__ spanv, const int* __restrict__ topk_idx,
    const float* __restrict__ antW, float* __restrict__ s_i, float* __restrict__ s_j) {
  int r = blockIdx.x;
  int idx = topk_idx[r];
  const unsigned short* row = spanv + (size_t)idx * DDIM;
  int t = threadIdx.x, lane = t & 63, wave = t >> 6;
  float pi = 0.f, pj = 0.f;
  for (int d = t; d < DDIM; d += 256) {
    float v = bf16u_to_f32(row[d]);
    pi += v * antW[d];
    pj += v * antW[DDIM + d];
  }
  for (int o = 32; o; o >>= 1) {
    pi += __shfl_down(pi, o, 64);
    pj += __shfl_down(pj, o, 64);
  }
  __shared__ float ri[4], rj[4];
  if (lane == 0) { ri[wave] = pi; rj[wave] = pj; }
  __syncthreads();
  if (t == 0) {
    s_i[r] = ri[0] + ri[1] + ri[2] + ri[3];
    s_j[r] = rj[0] + rj[1] + rj[2] + rj[3];
  }
}

// ---------------- final antecedent scores ----------------
__global__ void out_kernel(const float* __restrict__ s_i, const float* __restrict__ s_j,
                           const float* __restrict__ ant_b, float* __restrict__ out) {
  int idx = blockIdx.x * 256 + threadIdx.x;
  if (idx >= KTOP * (KTOP + 1)) return;
  int i = idx / (KTOP + 1), c = idx % (KTOP + 1);
  float v;
  if (c == 0) v = 0.f;
  else {
    int j = c - 1;
    v = (j >= i) ? -10000.f : (s_i[i] + s_j[j] + ant_b[0]);
  }
  out[idx] = v;
}

extern "C" void kernel_launch(void* const* d_in, const int* in_sizes, int n_in,
                              void* d_out, int out_size, void* d_ws, size_t ws_size,
                              hipStream_t stream) {
  const float* x      = (const float*)d_in[0];
  const int*   edges  = (const int*)d_in[1];
  const float* gcn_W  = (const float*)d_in[2];
  const float* gcn_b  = (const float*)d_in[3];
  const float* attn_w = (const float*)d_in[4];
  // d_in[5] attn_b: softmax-shift invariant, unused
  const float* ms_W1  = (const float*)d_in[6];
  const float* ms_b1  = (const float*)d_in[7];
  const float* ms_W2  = (const float*)d_in[8];
  // d_in[9] ms_b2: constant shift, doesn't affect top-k order or output
  const float* ant_W  = (const float*)d_in[10];
  const float* ant_b  = (const float*)d_in[11];
  const int* starts   = (const int*)d_in[12];
  const int* ends     = (const int*)d_in[13];
  // d_in[14] topk = 409 (hardcoded; fixed by problem sizes)

  size_t off = 0;
  char* wsb = (char*)d_ws;
  auto alloc = [&](size_t bytes) -> void* {
    void* p = wsb + off;
    off += (bytes + 255) & ~(size_t)255;
    return p;
  };
  unsigned short* Y     = (unsigned short*)alloc((size_t)NLBL * S_TOK * H_DIM * 2);  // 78.6 MB
  unsigned short* WtB   = (unsigned short*)alloc((size_t)NLBL * H_DIM * H_DIM * 2);  // 59.0 MB
  unsigned short* Wt2   = (unsigned short*)alloc((size_t)DDIM * DDIM * 2);           // 10.6 MB
  unsigned short* spanv = (unsigned short*)alloc((size_t)MPAD * DDIM * 2);           // 42.5 MB
  unsigned short* Xb    = (unsigned short*)alloc((size_t)S_TOK * H_DIM * 2);         // 1.5 MB
  int* seg_count  = (int*)alloc(NSEG * 4);
  int* tgt_count  = (int*)alloc(S_TOK * 4);
  int* tgt_off    = (int*)alloc((S_TOK + 4) * 4);
  int* cursor     = (int*)alloc(S_TOK * 4);
  int* sorted_row = (int*)alloc(NEDGE * 4);
  float* emb    = (float*)alloc((size_t)S_TOK * H_DIM * 4);
  float* scores = (float*)alloc(MPAD * 4);
  int* topk_idx = (int*)alloc(512 * 4);
  float* s_i    = (float*)alloc(512 * 4);
  float* s_j    = (float*)alloc(512 * 4);
  (void)ws_size; (void)in_sizes; (void)n_in; (void)out_size;

  hipMemsetAsync(seg_count, 0, NSEG * 4, stream);
  hipMemsetAsync(tgt_count, 0, S_TOK * 4, stream);
  hipMemsetAsync(cursor, 0, S_TOK * 4, stream);
  hipMemsetAsync(scores, 0, MPAD * 4, stream);

  dim3 b256(256);
  convert_bf16<<<(S_TOK * H_DIM / 2 + 255) / 256, b256, 0, stream>>>(x, (unsigned*)Xb,
                                                                     S_TOK * H_DIM / 2);
  // per-label transpose: WtB[l][d][h] = gcn_W[l][h][d]
  transpose_conv_b<<<dim3(H_DIM / 32, H_DIM / 32, NLBL), b256, 0, stream>>>(gcn_W, WtB, H_DIM, H_DIM);
  transpose_conv_b<<<dim3(DDIM / 32, DDIM / 32, 1), b256, 0, stream>>>(ms_W1, Wt2, DDIM, DDIM);
  edge_count2<<<NEDGE / 256, b256, 0, stream>>>(edges, seg_count, tgt_count);
  scan_t<<<1, 1024, 0, stream>>>(tgt_count, tgt_off);
  edge_scatter_t<<<NEDGE / 256, b256, 0, stream>>>(edges, tgt_off, cursor, sorted_row);
  // batched GEMM: Y_l = X @ W_l, 50 batches of (1024x768)@(768x768)
  gemm_bt_batched<<<dim3(48, NLBL), b256, 0, stream>>>((const __bf16*)Xb, (const __bf16*)WtB, Y);
  gather_emb_kernel<<<S_TOK, b256, 0, stream>>>(x, Y, tgt_off, sorted_row, seg_count, gcn_b, emb);
  span_kernel<<<(NSPAN + 3) / 4, b256, 0, stream>>>(emb, starts, ends, attn_w, spanv, NSPAN);
  // GEMM2: (9171 x 2304) @ (2304 x 2304) with fused relu(+b1)*W2 row-reduce epilogue
  gemm_score<<<72 * 18, b256, 0, stream>>>((const __bf16*)spanv, (const __bf16*)Wt2, scores,
                                           ms_b1, ms_W2, NSPAN, DDIM, DDIM, 72);
  topk_kernel<<<1, 1024, 0, stream>>>(scores, topk_idx);
  sij_kernel<<<KTOP, b256, 0, stream>>>(spanv, topk_idx, ant_W, s_i, s_j);
  out_kernel<<<(KTOP * (KTOP + 1) + 255) / 256, b256, 0, stream>>>(s_i, s_j, ant_b, (float*)d_out);
}